// Round 2
// baseline (98.382 us; speedup 1.0000x reference)
//
#include <hip/hip_runtime.h>
#include <math.h>

#define BQ 256   // batch
#define NXQ 256  // spatial points
#define TQ 100   // time steps
#define N2 512   // 2*B
#define DP 130   // LDS pitch (words): stride%32==2 -> worst 2-way conflict (free); *4%8==0 -> b64 aligned

// ---------------------------------------------------------------------------
// K1: blk<256:  rows b and b+256 of A/C:
//       A[r][x] = u[b,x,T-1] + rep[r,x]
//       C[r][x] = u[b,x,T-2] + rep[r,x] + upd(rep, dt, vs, dx)[x]
//     blk>=256: SS row (blk-256); blk==0,t==0 zeroes out[0] for row_kernel's atomics
// ---------------------------------------------------------------------------
__global__ __launch_bounds__(256) void prep_kernel(
    const float* __restrict__ x1, const float* __restrict__ x2,
    const float* __restrict__ u, const float* __restrict__ dt,
    const float* __restrict__ dx, const float* __restrict__ vs,
    float* __restrict__ A, float* __restrict__ C, float* __restrict__ SS,
    float* __restrict__ out) {
  int blk = blockIdx.x;
  int t = threadIdx.x;
  if (blk == 0 && t == 0) out[0] = 0.0f;
  if (blk < BQ) {
    int b = blk;
    __shared__ float w1[NXQ], w2[NXQ];
    w2[t] = x2[b * NXQ + t];  // reps row b      (first half = x2)
    w1[t] = x1[b * NXQ + t];  // reps row b+256  (second half = x1)
    __syncthreads();
    int tm = (t + NXQ - 1) & (NXQ - 1);
    int tp = (t + 1) & (NXQ - 1);
    float dtv = dt[b];
    float dxv = dx[0];
    float c0 = vs[b * 3 + 0], c1 = vs[b * 3 + 1], c2 = vs[b * 3 + 2];
    float2 uu = *(const float2*)&u[(size_t)(b * NXQ + t) * TQ + (TQ - 2)];
    {
      float w0 = w2[t], wm = w2[tm], wp = w2[tp];
      float upd = c0 * dtv * (wm - wp) * w0 / (2.0f * dxv)
                - c1 * dtv * (wm + wp - 2.0f * w0) / (dxv * dxv)
                - c2 * dtv * (w0 - wp) / dxv;
      A[b * NXQ + t] = uu.y + w0;
      C[b * NXQ + t] = uu.x + w0 + upd;
    }
    {
      float w0 = w1[t], wm = w1[tm], wp = w1[tp];
      float upd = c0 * dtv * (wm - wp) * w0 / (2.0f * dxv)
                - c1 * dtv * (wm + wp - 2.0f * w0) / (dxv * dxv)
                - c2 * dtv * (w0 - wp) / dxv;
      A[(b + BQ) * NXQ + t] = uu.y + w0;
      C[(b + BQ) * NXQ + t] = uu.x + w0 + upd;
    }
  } else {
    int i = blk - BQ;
    int j = t;
    float vi0 = vs[i * 3], vi1 = vs[i * 3 + 1], vi2 = vs[i * 3 + 2];
    float vj0 = vs[j * 3], vj1 = vs[j * 3 + 1], vj2 = vs[j * 3 + 2];
    float nvi = sqrtf(vi0 * vi0 + vi1 * vi1 + vi2 * vi2);
    float nvj = sqrtf(vj0 * vj0 + vj1 * vj1 + vj2 * vj2);
    float prod = sqrtf(fabsf(vi0 * vj0) + fabsf(vi1 * vj1) + fabsf(vi2 * vj2));
    float sim = prod / fmaxf(nvi, nvj);
    float ssv = 1.0f - 0.9f * sim;
    if (isnan(ssv)) ssv = 0.0f;
    SS[i * BQ + j] = ssv;
  }
}

// ---------------------------------------------------------------------------
// K2: SIM[i][j] = sum_x (A[j][x] - C[i][x])^2
//     32x32 tile / block, 2x2 register tile / thread, K chunked at 128.
//     LDS: 2 * 32 * 130 * 4 = 33.3 KB. float2 reads, 2-way conflicts max.
// ---------------------------------------------------------------------------
__global__ __launch_bounds__(256) void dist_kernel(const float* __restrict__ A,
                                                   const float* __restrict__ C,
                                                   float* __restrict__ SIM) {
  __shared__ float At[32 * DP];
  __shared__ float Ct[32 * DP];
  int t = threadIdx.x;
  int i0 = blockIdx.y * 32;
  int j0 = blockIdx.x * 32;
  int ci = (t >> 4) * 2;   // C rows: 0,2,...,30
  int aj = (t & 15) * 2;   // A rows (= SIM cols): 0,2,...,30
  float acc00 = 0.f, acc01 = 0.f, acc10 = 0.f, acc11 = 0.f;
  for (int ch = 0; ch < 2; ++ch) {
    // stage 32 rows x 128 x: 2048 float2 per array, 8 per thread, coalesced
    #pragma unroll
    for (int k = 0; k < 8; ++k) {
      int fidx = k * 256 + t;
      int row = fidx >> 6;      // 64 float2 per row
      int xi = (fidx & 63) * 2;
      float2 av = *(const float2*)&A[(j0 + row) * NXQ + ch * 128 + xi];
      float2 cv = *(const float2*)&C[(i0 + row) * NXQ + ch * 128 + xi];
      *(float2*)&At[row * DP + xi] = av;
      *(float2*)&Ct[row * DP + xi] = cv;
    }
    __syncthreads();
    #pragma unroll 4
    for (int x = 0; x < 128; x += 2) {
      float2 a0 = *(float2*)&At[aj * DP + x];
      float2 a1 = *(float2*)&At[(aj + 1) * DP + x];
      float2 c0 = *(float2*)&Ct[ci * DP + x];
      float2 c1 = *(float2*)&Ct[(ci + 1) * DP + x];
      float d;
      d = a0.x - c0.x; acc00 = fmaf(d, d, acc00);
      d = a0.y - c0.y; acc00 = fmaf(d, d, acc00);
      d = a1.x - c0.x; acc01 = fmaf(d, d, acc01);
      d = a1.y - c0.y; acc01 = fmaf(d, d, acc01);
      d = a0.x - c1.x; acc10 = fmaf(d, d, acc10);
      d = a0.y - c1.y; acc10 = fmaf(d, d, acc10);
      d = a1.x - c1.x; acc11 = fmaf(d, d, acc11);
      d = a1.y - c1.y; acc11 = fmaf(d, d, acc11);
    }
    __syncthreads();
  }
  *(float2*)&SIM[(i0 + ci) * N2 + j0 + aj]     = make_float2(acc00, acc01);
  *(float2*)&SIM[(i0 + ci + 1) * N2 + j0 + aj] = make_float2(acc10, acc11);
}

// ---------------------------------------------------------------------------
// K3: one wave per row r: logits = {pos} U {SIM[r][j]*ss : j not in {r, r+-B}};
//     wave-local max + expf sum -> lse; lane0 atomicAdds (lse - pos)/512.
// ---------------------------------------------------------------------------
__global__ __launch_bounds__(256) void row_kernel(const float* __restrict__ SIM,
                                                  const float* __restrict__ SS,
                                                  float* __restrict__ out) {
  int t = threadIdx.x;
  int wave = t >> 6, lane = t & 63;
  int r = blockIdx.x * 4 + wave;
  int rb = r & (BQ - 1);
  int jstar = (r + BQ) & (N2 - 1);
  const float* srow = SIM + r * N2;
  float pos = srow[jstar];
  float v[8];
  #pragma unroll
  for (int k = 0; k < 8; ++k) {
    int j = lane + k * 64;
    float s = srow[j];
    float w = SS[rb * BQ + (j & (BQ - 1))];
    float val = s * w;
    if (j == jstar) val = pos;
    else if ((j & (BQ - 1)) == rb) val = -INFINITY;  // excluded (j == r mod B, non-positive)
    v[k] = val;
  }
  float m = v[0];
  #pragma unroll
  for (int k = 1; k < 8; ++k) m = fmaxf(m, v[k]);
  #pragma unroll
  for (int off = 32; off > 0; off >>= 1) m = fmaxf(m, __shfl_xor(m, off, 64));
  float S = 0.f;
  #pragma unroll
  for (int k = 0; k < 8; ++k) S += expf(v[k] - m);  // expf(-inf)=0 handles excluded
  #pragma unroll
  for (int off = 32; off > 0; off >>= 1) S += __shfl_xor(S, off, 64);
  if (lane == 0) {
    double lse = (double)m + log((double)S);
    atomicAdd(out, (float)((lse - (double)pos) * (1.0 / (double)N2)));
  }
}

extern "C" void kernel_launch(void* const* d_in, const int* in_sizes, int n_in,
                              void* d_out, int out_size, void* d_ws, size_t ws_size,
                              hipStream_t stream) {
  const float* x1 = (const float*)d_in[0];  // [B, NX, 1, 1]
  const float* x2 = (const float*)d_in[1];  // [B, NX, 1, 1]
  const float* u  = (const float*)d_in[2];  // [B, NX, T]
  const float* dt = (const float*)d_in[3];  // [B]
  const float* dx = (const float*)d_in[4];  // [1]
  const float* vs = (const float*)d_in[5];  // [B, 3]
  char* ws = (char*)d_ws;
  float* SIM = (float*)(ws + 0);        // 512*512*4 = 1 MB
  float* A   = (float*)(ws + 1048576);  // 512*256*4 = 512 KB
  float* C   = (float*)(ws + 1572864);  // 512 KB
  float* SS  = (float*)(ws + 2097152);  // 256*256*4 = 256 KB
  float* out = (float*)d_out;

  prep_kernel<<<N2, 256, 0, stream>>>(x1, x2, u, dt, dx, vs, A, C, SS, out);
  dim3 g2(N2 / 32, N2 / 32);
  dist_kernel<<<g2, 256, 0, stream>>>(A, C, SIM);
  row_kernel<<<N2 / 4, 256, 0, stream>>>(SIM, SS, out);
}

// Round 3
// 97.685 us; speedup vs baseline: 1.0071x; 1.0071x over previous
//
#include <hip/hip_runtime.h>
#include <math.h>

#define BQ 256   // batch
#define NXQ 256  // spatial points
#define TQ 100   // time steps
#define N2 512   // 2*B
#define DP 258   // LDS pitch (words): even (b64-aligned), %32==2 -> even-row bank
                 // offsets step by 4 -> 8 groups x 2-way = conflict-free (m136)

// ---------------------------------------------------------------------------
// K1: block b (<256) builds rows b and b+256 of A/C:
//       A[r][x] = u[b,x,T-1] + rep[r,x]
//       C[r][x] = u[b,x,T-2] + rep[r,x] + upd(rep, dt, vs, dx)[x]
//     rep = concat([x2, x1]); also zeroes out[0] for K3's atomics.
// ---------------------------------------------------------------------------
__global__ __launch_bounds__(256) void prep_kernel(
    const float* __restrict__ x1, const float* __restrict__ x2,
    const float* __restrict__ u, const float* __restrict__ dt,
    const float* __restrict__ dx, const float* __restrict__ vs,
    float* __restrict__ A, float* __restrict__ C, float* __restrict__ out) {
  int b = blockIdx.x;
  int t = threadIdx.x;
  if (b == 0 && t == 0) out[0] = 0.0f;
  __shared__ float w1[NXQ], w2[NXQ];
  w2[t] = x2[b * NXQ + t];  // reps row b      (first half = x2)
  w1[t] = x1[b * NXQ + t];  // reps row b+256  (second half = x1)
  __syncthreads();
  int tm = (t + NXQ - 1) & (NXQ - 1);
  int tp = (t + 1) & (NXQ - 1);
  float dtv = dt[b];
  float dxv = dx[0];
  float c0 = vs[b * 3 + 0], c1 = vs[b * 3 + 1], c2 = vs[b * 3 + 2];
  float2 uu = *(const float2*)&u[(size_t)(b * NXQ + t) * TQ + (TQ - 2)];
  {
    float w0 = w2[t], wm = w2[tm], wp = w2[tp];
    float upd = c0 * dtv * (wm - wp) * w0 / (2.0f * dxv)
              - c1 * dtv * (wm + wp - 2.0f * w0) / (dxv * dxv)
              - c2 * dtv * (w0 - wp) / dxv;
    A[b * NXQ + t] = uu.y + w0;
    C[b * NXQ + t] = uu.x + w0 + upd;
  }
  {
    float w0 = w1[t], wm = w1[tm], wp = w1[tp];
    float upd = c0 * dtv * (wm - wp) * w0 / (2.0f * dxv)
              - c1 * dtv * (wm + wp - 2.0f * w0) / (dxv * dxv)
              - c2 * dtv * (w0 - wp) / dxv;
    A[(b + BQ) * NXQ + t] = uu.y + w0;
    C[(b + BQ) * NXQ + t] = uu.x + w0 + upd;
  }
}

// ---------------------------------------------------------------------------
// K2: SIM[i][j] = sum_x (A[j][x] - C[i][x])^2
//     32x32 tile / block, 2x2 register tile / thread, full K=256 in LDS
//     (2 * 32 * 258 * 4 = 66 KB). One stage + one barrier.
// ---------------------------------------------------------------------------
__global__ __launch_bounds__(256) void dist_kernel(const float* __restrict__ A,
                                                   const float* __restrict__ C,
                                                   float* __restrict__ SIM) {
  __shared__ float At[32 * DP];
  __shared__ float Ct[32 * DP];
  int t = threadIdx.x;
  int i0 = blockIdx.y * 32;
  int j0 = blockIdx.x * 32;
  // stage 32 rows x 256 x per array: 2048 float4 per array, 8 per thread
  #pragma unroll
  for (int k = 0; k < 8; ++k) {
    int fidx = k * 256 + t;
    int row = fidx >> 6;       // 64 float4 per row
    int xi = (fidx & 63) * 4;
    float4 av = *(const float4*)&A[(j0 + row) * NXQ + xi];
    float4 cv = *(const float4*)&C[(i0 + row) * NXQ + xi];
    *(float2*)&At[row * DP + xi]     = make_float2(av.x, av.y);
    *(float2*)&At[row * DP + xi + 2] = make_float2(av.z, av.w);
    *(float2*)&Ct[row * DP + xi]     = make_float2(cv.x, cv.y);
    *(float2*)&Ct[row * DP + xi + 2] = make_float2(cv.z, cv.w);
  }
  __syncthreads();
  int ci = (t >> 4) * 2;   // C rows: 0,2,...,30
  int aj = (t & 15) * 2;   // A rows (= SIM cols): 0,2,...,30
  float acc00 = 0.f, acc01 = 0.f, acc10 = 0.f, acc11 = 0.f;
  #pragma unroll 4
  for (int x = 0; x < NXQ; x += 2) {
    float2 a0 = *(float2*)&At[aj * DP + x];
    float2 a1 = *(float2*)&At[(aj + 1) * DP + x];
    float2 c0 = *(float2*)&Ct[ci * DP + x];
    float2 c1 = *(float2*)&Ct[(ci + 1) * DP + x];
    float d;
    d = a0.x - c0.x; acc00 = fmaf(d, d, acc00);
    d = a0.y - c0.y; acc00 = fmaf(d, d, acc00);
    d = a1.x - c0.x; acc01 = fmaf(d, d, acc01);
    d = a1.y - c0.y; acc01 = fmaf(d, d, acc01);
    d = a0.x - c1.x; acc10 = fmaf(d, d, acc10);
    d = a0.y - c1.y; acc10 = fmaf(d, d, acc10);
    d = a1.x - c1.x; acc11 = fmaf(d, d, acc11);
    d = a1.y - c1.y; acc11 = fmaf(d, d, acc11);
  }
  *(float2*)&SIM[(i0 + ci) * N2 + j0 + aj]     = make_float2(acc00, acc01);
  *(float2*)&SIM[(i0 + ci + 1) * N2 + j0 + aj] = make_float2(acc10, acc11);
}

// ---------------------------------------------------------------------------
// K3: one wave per row r. ss weights computed inline from vs (no SS matrix).
//     logits = {pos} U {SIM[r][j]*ss(rb, j%B) : j not in {r, r+-B}};
//     wave max + expf sum -> lse; lane0 atomicAdds (lse - pos)/512.
// ---------------------------------------------------------------------------
__global__ __launch_bounds__(256) void row_kernel(const float* __restrict__ SIM,
                                                  const float* __restrict__ vs,
                                                  float* __restrict__ out) {
  int t = threadIdx.x;
  int wave = t >> 6, lane = t & 63;
  int r = blockIdx.x * 4 + wave;
  int rb = r & (BQ - 1);
  int jstar = (r + BQ) & (N2 - 1);
  const float* srow = SIM + r * N2;
  float pos = srow[jstar];
  float vi0 = vs[rb * 3], vi1 = vs[rb * 3 + 1], vi2 = vs[rb * 3 + 2];
  float nvi = sqrtf(vi0 * vi0 + vi1 * vi1 + vi2 * vi2);
  float v[8];
  #pragma unroll
  for (int k = 0; k < 8; ++k) {
    int j = lane + k * 64;
    int jb = j & (BQ - 1);
    float s = srow[j];
    float vj0 = vs[jb * 3], vj1 = vs[jb * 3 + 1], vj2 = vs[jb * 3 + 2];
    float nvj = sqrtf(vj0 * vj0 + vj1 * vj1 + vj2 * vj2);
    float prod = sqrtf(fabsf(vi0 * vj0) + fabsf(vi1 * vj1) + fabsf(vi2 * vj2));
    float sim = prod / fmaxf(nvi, nvj);
    float ssv = 1.0f - 0.9f * sim;
    if (isnan(ssv)) ssv = 0.0f;
    float val = s * ssv;
    if (j == jstar) val = pos;
    else if (jb == rb) val = -INFINITY;  // excluded (j == r mod B, non-positive)
    v[k] = val;
  }
  float m = v[0];
  #pragma unroll
  for (int k = 1; k < 8; ++k) m = fmaxf(m, v[k]);
  #pragma unroll
  for (int off = 32; off > 0; off >>= 1) m = fmaxf(m, __shfl_xor(m, off, 64));
  float S = 0.f;
  #pragma unroll
  for (int k = 0; k < 8; ++k) S += expf(v[k] - m);  // expf(-inf)=0 handles excluded
  #pragma unroll
  for (int off = 32; off > 0; off >>= 1) S += __shfl_xor(S, off, 64);
  if (lane == 0) {
    double lse = (double)m + log((double)S);
    atomicAdd(out, (float)((lse - (double)pos) * (1.0 / (double)N2)));
  }
}

extern "C" void kernel_launch(void* const* d_in, const int* in_sizes, int n_in,
                              void* d_out, int out_size, void* d_ws, size_t ws_size,
                              hipStream_t stream) {
  const float* x1 = (const float*)d_in[0];  // [B, NX, 1, 1]
  const float* x2 = (const float*)d_in[1];  // [B, NX, 1, 1]
  const float* u  = (const float*)d_in[2];  // [B, NX, T]
  const float* dt = (const float*)d_in[3];  // [B]
  const float* dx = (const float*)d_in[4];  // [1]
  const float* vs = (const float*)d_in[5];  // [B, 3]
  char* ws = (char*)d_ws;
  float* SIM = (float*)(ws + 0);        // 512*512*4 = 1 MB
  float* A   = (float*)(ws + 1048576);  // 512*256*4 = 512 KB
  float* C   = (float*)(ws + 1572864);  // 512 KB
  float* out = (float*)d_out;

  prep_kernel<<<BQ, 256, 0, stream>>>(x1, x2, u, dt, dx, vs, A, C, out);
  dim3 g2(N2 / 32, N2 / 32);
  dist_kernel<<<g2, 256, 0, stream>>>(A, C, SIM);
  row_kernel<<<N2 / 4, 256, 0, stream>>>(SIM, vs, out);
}